// Round 16
// baseline (457.153 us; speedup 1.0000x reference)
//
#include <hip/hip_runtime.h>

typedef __bf16 bf16x8 __attribute__((ext_vector_type(8)));
typedef float  f32x4  __attribute__((ext_vector_type(4)));
typedef unsigned short u16x8 __attribute__((ext_vector_type(8)));
typedef unsigned short u16x4 __attribute__((ext_vector_type(4)));

#define MFMA16(a, b, c) __builtin_amdgcn_mfma_f32_16x16x32_bf16((a), (b), (c), 0, 0, 0)

#define GLOAD16(g, l) __builtin_amdgcn_global_load_lds( \
    (const __attribute__((address_space(1))) void*)(g),  \
    (__attribute__((address_space(3))) void*)(l), 16, 0, 0)

__device__ __forceinline__ float bf2f(unsigned short u) {
    unsigned int x = ((unsigned int)u) << 16;
    return __builtin_bit_cast(float, x);
}
__device__ __forceinline__ unsigned short f2bf(float f) {
    unsigned int x = __builtin_bit_cast(unsigned int, f);
    x = x + 0x7FFFu + ((x >> 16) & 1u);
    return (unsigned short)(x >> 16);
}
// dtype flag: fp32 1.0 has low half-word 0x0000; bf16 1.0 is 0x3F80.
__device__ __forceinline__ bool is_f32(const unsigned short* tf) { return tf[0] == 0; }
__device__ __forceinline__ float ldscal(const void* p, int i, bool f32m) {
    return f32m ? ((const float*)p)[i] : bf2f(((const unsigned short*)p)[i]);
}

// ---------------------------------------------------------------------------
// prep_all: blocks [0,12288): dual transpose x -> xb,xbT + fused colsum
//           blocks [12288,13008): weight prep (WqkT / Wv slice / WprojT)
// (sB+beff zeroed via hipMemsetAsync before launch)
// ---------------------------------------------------------------------------
__device__ __forceinline__ void tr_tile(const void* in_, unsigned short* out,
                                        int R, int C, int istride,
                                        int bid, bool f32m, unsigned short* T)
{
    const int nct = C >> 6;
    const int tx = bid % nct;
    const int ty = bid / nct;
    const int r0 = ty * 64, c0 = tx * 64;
    const int t = threadIdx.x;
#pragma unroll
    for (int s = 0; s < 2; ++s) {
        const int idx = t + s * 256;
        const int rr = idx >> 3;
        const int cc = (idx & 7) * 8;
        unsigned short v[8];
        if (f32m) {
            const float* inf = (const float*)in_;
            f32x4 a = *(const f32x4*)&inf[(size_t)(r0 + rr) * istride + c0 + cc];
            f32x4 b = *(const f32x4*)&inf[(size_t)(r0 + rr) * istride + c0 + cc + 4];
#pragma unroll
            for (int j = 0; j < 4; ++j) { v[j] = f2bf(a[j]); v[4 + j] = f2bf(b[j]); }
        } else {
            u16x8 a = *(const u16x8*)&((const unsigned short*)in_)[(size_t)(r0 + rr) * istride + c0 + cc];
#pragma unroll
            for (int j = 0; j < 8; ++j) v[j] = a[j];
        }
#pragma unroll
        for (int j = 0; j < 8; ++j) T[(cc + j) * 72 + rr] = v[j];
    }
    __syncthreads();
#pragma unroll
    for (int s = 0; s < 2; ++s) {
        const int idx = t + s * 256;
        const int cc = idx >> 3;
        const int rr = (idx & 7) * 8;
        u16x8 v = *(const u16x8*)&T[cc * 72 + rr];
        *(u16x8*)&out[(size_t)(c0 + cc) * R + r0 + rr] = v;
    }
}

__global__ __launch_bounds__(256)
void prep_all(const void* __restrict__ x, unsigned short* __restrict__ xb,
              unsigned short* __restrict__ xbT, float* __restrict__ sB,
              const void* __restrict__ Wqkv, const void* __restrict__ Wp,
              unsigned short* __restrict__ WqkT, unsigned short* __restrict__ Wv_bf,
              unsigned short* __restrict__ WprojT, const unsigned short* __restrict__ tf)
{
    __shared__ unsigned short T[64 * 72];
    const bool f32m = is_f32(tf);
    if (blockIdx.x < 12288) {
        const int tx = blockIdx.x % 12;
        const int ty = blockIdx.x / 12;
        const int r0 = ty * 64, c0 = tx * 64;
        const int t = threadIdx.x;
#pragma unroll
        for (int s = 0; s < 2; ++s) {
            const int idx = t + s * 256;
            const int rr = idx >> 3;
            const int cc = (idx & 7) * 8;
            u16x8 v;
            if (f32m) {
                const float* inf = (const float*)x;
                f32x4 a = *(const f32x4*)&inf[(size_t)(r0 + rr) * 768 + c0 + cc];
                f32x4 b = *(const f32x4*)&inf[(size_t)(r0 + rr) * 768 + c0 + cc + 4];
#pragma unroll
                for (int j = 0; j < 4; ++j) { v[j] = f2bf(a[j]); v[4 + j] = f2bf(b[j]); }
            } else {
                v = *(const u16x8*)&((const unsigned short*)x)[(size_t)(r0 + rr) * 768 + c0 + cc];
            }
            *(u16x8*)&xb[(size_t)(r0 + rr) * 768 + c0 + cc] = v;
#pragma unroll
            for (int j = 0; j < 8; ++j) T[(cc + j) * 72 + rr] = v[j];
        }
        __syncthreads();
#pragma unroll
        for (int s = 0; s < 2; ++s) {
            const int idx = t + s * 256;
            const int cc = idx >> 3;
            const int rr = (idx & 7) * 8;
            u16x8 v = *(const u16x8*)&T[cc * 72 + rr];
            *(u16x8*)&xbT[(size_t)(c0 + cc) * 65536 + r0 + rr] = v;
        }
        {
            const int col = t >> 2;
            const int seg = t & 3;
            float s = 0.f;
#pragma unroll
            for (int r = 0; r < 16; ++r) s += bf2f(T[col * 72 + seg * 16 + r]);
            s += __shfl_xor(s, 1);
            s += __shfl_xor(s, 2);
            if (seg == 0) atomicAdd(&sB[(r0 >> 12) * 768 + c0 + col], s);
        }
    } else {
        const int bid = blockIdx.x - 12288;
        if (bid < 288) {
            tr_tile(Wqkv, WqkT, 768, 1536, 2304, bid, f32m, T);
        } else if (bid < 576) {
            const int t = (bid - 288) * 256 + threadIdx.x;
            const int c = t / 96;
            const int e0 = (t % 96) * 8;
            u16x8 v;
            if (f32m) {
                const float* p = (const float*)Wqkv + (size_t)c * 2304 + 1536 + e0;
                f32x4 a = *(const f32x4*)p;
                f32x4 b = *(const f32x4*)(p + 4);
#pragma unroll
                for (int j = 0; j < 4; ++j) { v[j] = f2bf(a[j]); v[4 + j] = f2bf(b[j]); }
            } else {
                v = *(const u16x8*)&((const unsigned short*)Wqkv)[(size_t)c * 2304 + 1536 + e0];
            }
            *(u16x8*)&Wv_bf[(size_t)c * 768 + e0] = v;
        } else {
            tr_tile(Wp, WprojT, 768, 768, 768, bid - 576, f32m, T);
        }
    }
}

// ---------------------------------------------------------------------------
// gemmG: G_b = xb_b^T xb_b, SYMMETRIC (21 of 36 tiles + mirror), validated
// rounds 11-15. 128x128, 4 waves, BK=64 dbuf, vmcnt(8).
// ---------------------------------------------------------------------------
__global__ __launch_bounds__(256, 2)
void gemmG(const unsigned short* __restrict__ A, unsigned short* __restrict__ G)
{
    constexpr int NT = 64;
    constexpr size_t LD = 65536;
    __shared__ __align__(16) char SM[65536];
    unsigned short* lds = (unsigned short*)SM;

    const int tid  = threadIdx.x;
    const int wave = tid >> 6;
    const int lane = tid & 63;
    const int wm   = wave >> 1;
    const int wn   = wave & 1;
    const int lr   = lane & 15;
    const int lq   = lane >> 4;

    const int per = gridDim.x >> 3;
    const int wg  = (blockIdx.x & 7) * per + (blockIdx.x >> 3);
    const int b = wg / 21;
    int rr21 = wg % 21;
    int mt = 0;
    while (rr21 >= 6 - mt) { rr21 -= 6 - mt; ++mt; }
    const int nt = mt + rr21;
    const size_t m0 = (size_t)mt * 128;
    const int n0 = nt * 128;

    const unsigned short* Ab = A + m0 * LD + (size_t)b * 4096;
    const unsigned short* Bb = A + (size_t)n0 * LD + (size_t)b * 4096;
    unsigned short* Gb = G + (size_t)b * 589824;

    f32x4 zero = {0.f, 0.f, 0.f, 0.f};
    f32x4 acc[4][4];
#pragma unroll
    for (int i = 0; i < 4; ++i)
#pragma unroll
        for (int j = 0; j < 4; ++j) acc[i][j] = zero;

    auto STAGE = [&](int t) {
        unsigned short* la_ = lds + (t & 1) * 16384;
        unsigned short* lb_ = la_ + 8192;
#pragma unroll
        for (int it = 0; it < 4; ++it) {
            const int c = it * 256 + tid;
            const int row = c >> 3;
            const int gs = (c & 7) ^ (row & 7);
            GLOAD16(Ab + (size_t)row * LD + t * 64 + gs * 8, la_ + c * 8);
        }
#pragma unroll
        for (int it = 0; it < 4; ++it) {
            const int c = it * 256 + tid;
            const int row = c >> 3;
            const int gs = (c & 7) ^ (row & 7);
            GLOAD16(Bb + (size_t)row * LD + t * 64 + gs * 8, lb_ + c * 8);
        }
    };

    STAGE(0);
    STAGE(1);

    for (int t = 0; t < NT; ++t) {
        if (t + 1 < NT) asm volatile("s_waitcnt vmcnt(8)" ::: "memory");
        else            asm volatile("s_waitcnt vmcnt(0)" ::: "memory");
        __builtin_amdgcn_s_barrier();
        __builtin_amdgcn_sched_barrier(0);

        const char* la = (const char*)(lds + (t & 1) * 16384);
        const char* lb = la + 16384;

        bf16x8 bfr[4][2], af[4][2];
#pragma unroll
        for (int ni = 0; ni < 4; ++ni)
#pragma unroll
            for (int ks = 0; ks < 2; ++ks) {
                const int row = wn * 64 + ni * 16 + lr;
                const int s   = ks * 4 + lq;
                bfr[ni][ks] = *(const bf16x8*)(lb + row * 128 + ((s ^ (row & 7)) << 4));
            }
#pragma unroll
        for (int mi = 0; mi < 4; ++mi)
#pragma unroll
            for (int ks = 0; ks < 2; ++ks) {
                const int row = wm * 64 + mi * 16 + lr;
                const int s   = ks * 4 + lq;
                af[mi][ks] = *(const bf16x8*)(la + row * 128 + ((s ^ (row & 7)) << 4));
            }
        __builtin_amdgcn_s_setprio(1);
#pragma unroll
        for (int mi = 0; mi < 4; ++mi)
#pragma unroll
            for (int ni = 0; ni < 4; ++ni)
#pragma unroll
                for (int ks = 0; ks < 2; ++ks)
                    acc[mi][ni] = MFMA16(af[mi][ks], bfr[ni][ks], acc[mi][ni]);
        __builtin_amdgcn_s_setprio(0);

        __builtin_amdgcn_sched_barrier(0);
        __builtin_amdgcn_s_barrier();
        if (t + 2 < NT) STAGE(t + 2);
    }

#pragma unroll
    for (int mi = 0; mi < 4; ++mi)
#pragma unroll
        for (int ni = 0; ni < 4; ++ni)
#pragma unroll
            for (int r = 0; r < 4; ++r) {
                const size_t row = m0 + (size_t)(wm * 64 + mi * 16 + lq * 4 + r);
                const int col = n0 + wn * 64 + ni * 16 + lr;
                Gb[row * 768 + col] = f2bf(acc[mi][ni][r]);
            }

    if (mt != nt) {
        asm volatile("s_waitcnt lgkmcnt(0)" ::: "memory");
        __builtin_amdgcn_s_barrier();
        unsigned short* CTw = (unsigned short*)SM + wave * (64 * 68);
#pragma unroll
        for (int mi = 0; mi < 4; ++mi)
#pragma unroll
            for (int ni = 0; ni < 4; ++ni) {
                u16x4 pk;
#pragma unroll
                for (int r = 0; r < 4; ++r) pk[r] = f2bf(acc[mi][ni][r]);
                *(u16x4*)&CTw[(ni * 16 + lr) * 68 + mi * 16 + lq * 4] = pk;
            }
#pragma unroll
        for (int rep = 0; rep < 8; ++rep) {
            const int idx = rep * 64 + lane;
            const int c = idx >> 3;
            const int j = (idx & 7) * 8;
            u16x8 v = *(const u16x8*)&CTw[c * 68 + j];
            const size_t rowT = (size_t)n0 + wn * 64 + c;
            const int colT = (int)m0 + wm * 64 + j;
            *(u16x8*)&Gb[rowT * 768 + colT] = v;
        }
    }
}

// ---------------------------------------------------------------------------
// gemmH: 128x256 tile, BK=32, 8 waves, TRIPLE-buffered LDS (72KB), single
// barrier per K-step (validated r14/r15 ledger: vmcnt(3) steady / 0 tail).
// MODE 1 f32 epilogue: LDS repack -> coalesced f32x4 stores (r15, +13%).
// MODE 1: out = xb @ PT_b + beff_b + bp   (grid 1536)
// MODE 2: PT  = MbT @ Wv                  (grid 288)
// ---------------------------------------------------------------------------
template<int MODE>
__global__ __launch_bounds__(512, 4)
void gemmH(const unsigned short* __restrict__ A,
           const unsigned short* __restrict__ BT,
           const float* __restrict__ bias,
           const void* __restrict__ bp,
           unsigned short* __restrict__ o0,
           float* __restrict__ oF,
           const unsigned short* __restrict__ tf)
{
    constexpr int K = 768, NT = 24;
    __shared__ __align__(16) char SM[73728];   // 3 bufs x (A 8KB + B 16KB)

    const bool f32m = is_f32(tf);
    const int tid  = threadIdx.x;
    const int wave = tid >> 6;
    const int lane = tid & 63;
    const int wm   = wave >> 2;
    const int wn   = wave & 3;
    const int lr   = lane & 15;
    const int lq   = lane >> 4;

    const int per = gridDim.x >> 3;
    const int wg  = (blockIdx.x & 7) * per + (blockIdx.x >> 3);
    const int mt = wg / 3, nt = wg % 3;
    const size_t m0 = (size_t)mt * 128;
    const int n0 = nt * 256;

    const unsigned short* Ab = A + m0 * K;
    const unsigned short* Bb;
    if (MODE == 1) Bb = BT + (m0 >> 12) * (size_t)589824 + (size_t)n0 * K;
    else           Bb = BT + (size_t)n0 * K;

    f32x4 zero = {0.f, 0.f, 0.f, 0.f};
    f32x4 acc[4][4];
#pragma unroll
    for (int i = 0; i < 4; ++i)
#pragma unroll
        for (int j = 0; j < 4; ++j) acc[i][j] = zero;

    auto STAGE = [&](int t) {
        char* base = SM + (t % 3) * 24576;
        {
            const int c = tid;                        // A: 128x32
            const int rp = c >> 3;
            const int ch = (c & 7) ^ (rp & 7);
            const int srow = rp * 2 + (ch >> 2);
            const int sk = (ch & 3) * 8;
            GLOAD16(Ab + (size_t)srow * K + t * 32 + sk, base + c * 16);
        }
#pragma unroll
        for (int ev = 0; ev < 2; ++ev) {
            const int c = ev * 512 + tid;             // B: 256x32
            const int rp = c >> 3;
            const int ch = (c & 7) ^ (rp & 7);
            const int srow = rp * 2 + (ch >> 2);
            const int sk = (ch & 3) * 8;
            GLOAD16(Bb + (size_t)srow * K + t * 32 + sk, base + 8192 + c * 16);
        }
    };

    STAGE(0);
    STAGE(1);

    for (int t = 0; t < NT; ++t) {
        if (t < NT - 1) asm volatile("s_waitcnt vmcnt(3)" ::: "memory");
        else            asm volatile("s_waitcnt vmcnt(0)" ::: "memory");
        __builtin_amdgcn_s_barrier();
        __builtin_amdgcn_sched_barrier(0);

        const char* la = SM + (t % 3) * 24576;
        const char* lb = la + 8192;

        bf16x8 af[4], bfr[4];
#pragma unroll
        for (int ni = 0; ni < 4; ++ni) {
            const int row = wn * 64 + ni * 16 + lr;
            const int rp = row >> 1;
            const int ch = (row & 1) * 4 + lq;
            bfr[ni] = *(const bf16x8*)(lb + rp * 128 + ((ch ^ (rp & 7)) << 4));
        }
#pragma unroll
        for (int mi = 0; mi < 4; ++mi) {
            const int row = wm * 64 + mi * 16 + lr;
            const int rp = row >> 1;
            const int ch = (row & 1) * 4 + lq;
            af[mi] = *(const bf16x8*)(la + rp * 128 + ((ch ^ (rp & 7)) << 4));
        }
        __builtin_amdgcn_s_setprio(1);
#pragma unroll
        for (int mi = 0; mi < 4; ++mi)
#pragma unroll
            for (int ni = 0; ni < 4; ++ni)
                acc[mi][ni] = MFMA16(af[mi], bfr[ni], acc[mi][ni]);
        __builtin_amdgcn_s_setprio(0);

        __builtin_amdgcn_sched_barrier(0);
        if (t + 2 < NT) STAGE(t + 2);
    }

    float bb[4];
#pragma unroll
    for (int ni = 0; ni < 4; ++ni) {
        const int col = n0 + wn * 64 + ni * 16 + lr;
        bb[ni] = (MODE == 1) ? (bias[(m0 >> 12) * 768 + col] + ldscal(bp, col, f32m)) : 0.f;
    }

    if (MODE == 1 && f32m) {
        // coalesced f32 store: repack through LDS (freed after loop drain)
        asm volatile("s_waitcnt lgkmcnt(0)" ::: "memory");
        __builtin_amdgcn_s_barrier();
        float* Lf = (float*)SM + wave * 2176;        // 32 rows x 68 f32
#pragma unroll
        for (int mh = 0; mh < 2; ++mh) {
#pragma unroll
            for (int mp = 0; mp < 2; ++mp)
#pragma unroll
                for (int ni = 0; ni < 4; ++ni)
#pragma unroll
                    for (int r = 0; r < 4; ++r) {
                        const int lrow = mp * 16 + lq * 4 + r;
                        const int lcol = ni * 16 + lr;
                        Lf[lrow * 68 + lcol] = acc[mh * 2 + mp][ni][r] + bb[ni];
                    }
#pragma unroll
            for (int rr = 0; rr < 8; ++rr) {
                const int lrow = rr * 4 + lq;
                const int lcol = lr * 4;
                f32x4 v = *(const f32x4*)&Lf[lrow * 68 + lcol];
                const size_t grow = m0 + (size_t)(wm * 64 + mh * 32 + lrow);
                *(f32x4*)&oF[grow * 768 + n0 + wn * 64 + lcol] = v;
            }
        }
    } else {
#pragma unroll
        for (int mi = 0; mi < 4; ++mi)
#pragma unroll
            for (int ni = 0; ni < 4; ++ni)
#pragma unroll
                for (int r = 0; r < 4; ++r) {
                    const size_t row = m0 + (size_t)(wm * 64 + mi * 16 + lq * 4 + r);
                    const int col = n0 + wn * 64 + ni * 16 + lr;
                    const float val = acc[mi][ni][r] + bb[ni];
                    o0[row * 768 + col] = f2bf(val);
                }
    }
}

// ---------------------------------------------------------------------------
// attnG: fused P-slice + attn + mb_build + beff (replaces gemmH<4>+attn_mb).
// Grid 192 (b,h), 512 thr, ~130KB LDS (1 block/CU, single round).
// Uses G symmetric: Y = W_slice · G_b via BT-form MFMA with BT = G rows.
//  ph1: Yl = A_q·G_b  (wave w -> cols [w*96,w*96+96), acc[4][6], K=768)
//  ph2: nq[d]=dot(Yl[d],Wq[d]); uq[d]=dot(sb,Wq[d])
//  ph3: S[d][e]=sum_c Yl[d][c]·Wk[e][c]  (8-wave k-split + seq reduce)
//  ph4: Yl = A_k·G_b (overwrite)  ph5: nk/uk dots
//  ph6: softmax (rank-1 bias corrections) -> Pl
//  ph7: MbT MFMA vs WprojT + beff atomics
// ---------------------------------------------------------------------------
__global__ __launch_bounds__(512)
void attnG(const unsigned short* __restrict__ G,
           const unsigned short* __restrict__ WqkT,
           const float* __restrict__ s,
           const void* __restrict__ bqkv,
           const unsigned short* __restrict__ WprojT,
           const unsigned short* __restrict__ tf,
           unsigned short* __restrict__ MbT,
           float* __restrict__ beff)
{
    constexpr int YLD = 776;                 // u16 stride: 2-way banks, 16B aligned
    __shared__ unsigned short Yl[64 * YLD];  // 99328 B
    __shared__ float S[64][64];
    __shared__ float nq[64], nk[64], uq[64], uk[64];
    __shared__ float sb[768];
    __shared__ float bkv[64];
    __shared__ float bvv[64];
    __shared__ unsigned short Pl[64 * 72];
    const bool f32m = is_f32(tf);
    const int per = gridDim.x >> 3;
    const int bh = (blockIdx.x & 7) * per + (blockIdx.x >> 3);   // XCD swizzle
    const int b = bh / 12, h = bh % 12;
    const unsigned short* Gb = G + (size_t)b * 589824;
    const unsigned short* Wq = WqkT + (size_t)(h * 64) * 768;
    const unsigned short* Wk = Wq + 589824;
    const int tid = threadIdx.x;
    const int wave = tid >> 6;
    const int lane = tid & 63;
    const int lr = lane & 15;
    const int lq = lane >> 4;

    for (int i = tid; i < 768; i += 512) sb[i] = s[b * 768 + i];
    if (tid < 64)       bkv[tid] = ldscal(bqkv, 768 + h * 64 + tid, f32m);
    else if (tid < 128) bvv[tid - 64] = ldscal(bqkv, 1536 + h * 64 + (tid - 64), f32m);

    f32x4 zero = {0.f, 0.f, 0.f, 0.f};

    // --- Y = W_slice · G_b (BT-form, G symmetric). wave w -> 96-col chunk.
    auto COMP_Y = [&](const unsigned short* Ws) {
        f32x4 acy[4][6];
#pragma unroll
        for (int i = 0; i < 4; ++i)
#pragma unroll
            for (int j = 0; j < 6; ++j) acy[i][j] = zero;
        const int c0 = wave * 96;
        for (int ks = 0; ks < 24; ++ks) {
            bf16x8 af[4], bfr[6];
#pragma unroll
            for (int mi = 0; mi < 4; ++mi)
                af[mi] = *(const bf16x8*)&Ws[(size_t)(mi * 16 + lr) * 768 + ks * 32 + lq * 8];
#pragma unroll
            for (int ni = 0; ni < 6; ++ni)
                bfr[ni] = *(const bf16x8*)&Gb[(size_t)(c0 + ni * 16 + lr) * 768 + ks * 32 + lq * 8];
#pragma unroll
            for (int mi = 0; mi < 4; ++mi)
#pragma unroll
                for (int ni = 0; ni < 6; ++ni)
                    acy[mi][ni] = MFMA16(af[mi], bfr[ni], acy[mi][ni]);
        }
#pragma unroll
        for (int mi = 0; mi < 4; ++mi)
#pragma unroll
            for (int ni = 0; ni < 6; ++ni)
#pragma unroll
                for (int r = 0; r < 4; ++r)
                    Yl[(mi * 16 + lq * 4 + r) * YLD + c0 + ni * 16 + lr] = f2bf(acy[mi][ni][r]);
    };

    const int d   = tid >> 3;
    const int oct = tid & 7;

    // dots of Yl row d and W row d over oct's 96-chunk + sb dot
    auto DOTS = [&](const unsigned short* Ws, float* nd, float* ud) {
        const unsigned short* wr = Ws + (size_t)d * 768 + oct * 96;
        const unsigned short* yr = &Yl[d * YLD + oct * 96];
        float a_n = 0.f, a_u = 0.f;
        for (int i = 0; i < 12; ++i) {
            u16x8 vy = *(const u16x8*)&yr[i * 8];
            u16x8 vw = *(const u16x8*)&wr[i * 8];
#pragma unroll
            for (int j = 0; j < 8; ++j) {
                const float wv = bf2f(vw[j]);
                a_n += bf2f(vy[j]) * wv;
                a_u += sb[oct * 96 + i * 8 + j] * wv;
            }
        }
        a_n += __shfl_xor(a_n, 1); a_n += __shfl_xor(a_n, 2); a_n += __shfl_xor(a_n, 4);
        a_u += __shfl_xor(a_u, 1); a_u += __shfl_xor(a_u, 2); a_u += __shfl_xor(a_u, 4);
        if (oct == 0) { nd[d] = a_n; ud[d] = a_u; }
    };

    // ---- phase 1: Yq
    COMP_Y(Wq);
    __syncthreads();
    // ---- phase 2: nq/uq
    DOTS(Wq, nq, uq);
    // ---- phase 3: S[d][e] = sum_c Yl[d][c] Wk[e][c]; wave k-split 96
    f32x4 accs[4][4];
#pragma unroll
    for (int i = 0; i < 4; ++i)
#pragma unroll
        for (int j = 0; j < 4; ++j) accs[i][j] = zero;
    {
        const int cc0 = wave * 96;
        for (int ks = 0; ks < 3; ++ks) {
            bf16x8 af[4], bfr[4];
#pragma unroll
            for (int mi = 0; mi < 4; ++mi)
                af[mi] = *(const bf16x8*)&Yl[(mi * 16 + lr) * YLD + cc0 + ks * 32 + lq * 8];
#pragma unroll
            for (int ni = 0; ni < 4; ++ni)
                bfr[ni] = *(const bf16x8*)&Wk[(size_t)(ni * 16 + lr) * 768 + cc0 + ks * 32 + lq * 8];
#pragma unroll
            for (int mi = 0; mi < 4; ++mi)
#pragma unroll
                for (int ni = 0; ni < 4; ++ni)
                    accs[mi][ni] = MFMA16(af[mi], bfr[ni], accs[mi][ni]);
        }
    }
    __syncthreads();
    for (int ww = 0; ww < 8; ++ww) {
        if (wave == ww) {
#pragma unroll
            for (int mi = 0; mi < 4; ++mi)
#pragma unroll
                for (int ni = 0; ni < 4; ++ni)
#pragma unroll
                    for (int r = 0; r < 4; ++r) {
                        const int dd = mi * 16 + lq * 4 + r;
                        const int e = ni * 16 + lr;
                        if (ww == 0) S[dd][e] = accs[mi][ni][r];
                        else         S[dd][e] += accs[mi][ni][r];
                    }
        }
        __syncthreads();
    }
    // ---- phase 4: Yk overwrites Yl (all Yl reads are complete: ph2 dots and
    // ph3 A-frags precede each wave's reduce barriers above)
    COMP_Y(Wk);
    __syncthreads();
    // ---- phase 5: nk/uk
    DOTS(Wk, nk, uk);
    __syncthreads();

    // ---- phase 6: softmax with rank-1 bias corrections -> Pl
    {
        const float tv  = f32m ? ((const float*)tf)[h] : bf2f(tf[h]);
        const float bqd = ldscal(bqkv, h * 64 + d, f32m);
        const float uqd = uq[d];
        const float nqf = nq[d] + 2.f * bqd * uqd + 4096.f * bqd * bqd;
        const float qn  = fmaxf(sqrtf(fmaxf(nqf, 0.f)), 1e-12f);
        float vals[8];
        float mx = -1e30f;
#pragma unroll
        for (int i = 0; i < 8; ++i) {
            const int e = oct * 8 + i;
            const float bke = bkv[e];
            const float nkf = nk[e] + 2.f * bke * uk[e] + 4096.f * bke * bke;
            const float kn  = fmaxf(sqrtf(fmaxf(nkf, 0.f)), 1e-12f);
            const float sv  = S[d][e] + bqd * uk[e] + uqd * bke + 4096.f * bqd * bke;
            const float val = sv / (qn * kn) * tv;
            vals[i] = val;
            mx = fmaxf(mx, val);
        }
        mx = fmaxf(mx, __shfl_xor(mx, 1));
        mx = fmaxf(mx, __shfl_xor(mx, 2));
        mx = fmaxf(mx, __shfl_xor(mx, 4));
        float sum = 0.f;
#pragma unroll
        for (int i = 0; i < 8; ++i) { vals[i] = __expf(vals[i] - mx); sum += vals[i]; }
        sum += __shfl_xor(sum, 1);
        sum += __shfl_xor(sum, 2);
        sum += __shfl_xor(sum, 4);
        const float inv = 1.0f / sum;
#pragma unroll
        for (int i = 0; i < 8; ++i) {
            const int e = oct * 8 + i;
            Pl[e * 72 + d] = f2bf(vals[i] * inv);
        }
    }
    __syncthreads();

    // ---- phase 7: MbT[b][j][(h,e)] = sum_d Pl[e][d] WprojT[j][(h,d)]
    f32x4 accm[4][6];
#pragma unroll
    for (int i = 0; i < 4; ++i)
#pragma unroll
        for (int j = 0; j < 6; ++j) accm[i][j] = zero;
#pragma unroll
    for (int ks = 0; ks < 2; ++ks) {
        bf16x8 af[4], bfr[6];
#pragma unroll
        for (int mi = 0; mi < 4; ++mi)
            af[mi] = *(const bf16x8*)&Pl[(mi * 16 + lr) * 72 + ks * 32 + lq * 8];
#pragma unroll
        for (int ni = 0; ni < 6; ++ni) {
            const int j = wave * 96 + ni * 16 + lr;
            bfr[ni] = *(const bf16x8*)&WprojT[(size_t)j * 768 + h * 64 + ks * 32 + lq * 8];
        }
#pragma unroll
        for (int mi = 0; mi < 4; ++mi)
#pragma unroll
            for (int ni = 0; ni < 6; ++ni)
                accm[mi][ni] = MFMA16(af[mi], bfr[ni], accm[mi][ni]);
    }

#pragma unroll
    for (int ni = 0; ni < 6; ++ni) {
        const int j = wave * 96 + ni * 16 + lr;
        float part = 0.f;
#pragma unroll
        for (int mi = 0; mi < 4; ++mi) {
            const int e = mi * 16 + lq * 4;
            u16x4 pk;
#pragma unroll
            for (int r = 0; r < 4; ++r) {
                pk[r] = f2bf(accm[mi][ni][r]);
                part += accm[mi][ni][r] * bvv[e + r];
            }
            *(u16x4*)&MbT[(size_t)b * 589824 + (size_t)j * 768 + h * 64 + e] = pk;
        }
        atomicAdd(&beff[b * 768 + j], part);
    }
}

// ---------------------------------------------------------------------------
extern "C" void kernel_launch(void* const* d_in, const int* in_sizes, int n_in,
                              void* d_out, int out_size, void* d_ws, size_t ws_size,
                              hipStream_t stream)
{
    const void* x    = d_in[0];
    const void* Wqkv = d_in[1];
    const void* bqkv = d_in[2];
    const void* Wp   = d_in[3];
    const void* bp   = d_in[4];
    const unsigned short* tf = (const unsigned short*)d_in[5];

    char* w = (char*)d_ws;
    unsigned short* xbT    = (unsigned short*)(w);                  // [768][65536]
    unsigned short* xb     = (unsigned short*)(w + 100663296);      // [65536][768]
    unsigned short* G      = (unsigned short*)(w + 201326592);      // [16][768][768]
    unsigned short* PT     = (unsigned short*)(w + 257949696);      // [16][768][768]
    unsigned short* MbT    = (unsigned short*)(w + 276824064);      // [16][768][768]
    unsigned short* WqkT   = (unsigned short*)(w + 295698432);      // [1536][768]
    unsigned short* Wv_bf  = (unsigned short*)(w + 298057728);      // [768][768]
    unsigned short* WprojT = (unsigned short*)(w + 299237376);      // [768][768]
    float*          sB     = (float*)(w + 301989888);               // [16][768]
    float*          beff   = (float*)(w + 302039040);               // [16][768]
    // total ws use: 302088192 B

    hipMemsetAsync(sB, 0, 98304, stream);   // sB + beff (adjacent)
    prep_all<<<dim3(13008), dim3(256), 0, stream>>>(x, xb, xbT, sB, Wqkv, Wp,
                                                    WqkT, Wv_bf, WprojT, tf);

    gemmG<<<dim3(336), dim3(256), 0, stream>>>(xbT, G);
    attnG<<<dim3(192), dim3(512), 0, stream>>>(G, WqkT, sB, bqkv, WprojT, tf, MbT, beff);
    gemmH<2><<<dim3(288), dim3(512), 0, stream>>>(MbT, Wv_bf, nullptr, nullptr, PT, nullptr, tf);
    gemmH<1><<<dim3(1536), dim3(512), 0, stream>>>(xb, PT, beff, bp,
        (unsigned short*)d_out, (float*)d_out, tf);
}

// Round 17
// 404.862 us; speedup vs baseline: 1.1292x; 1.1292x over previous
//
#include <hip/hip_runtime.h>

typedef __bf16 bf16x8 __attribute__((ext_vector_type(8)));
typedef float  f32x4  __attribute__((ext_vector_type(4)));
typedef unsigned short u16x8 __attribute__((ext_vector_type(8)));
typedef unsigned short u16x4 __attribute__((ext_vector_type(4)));

#define MFMA16(a, b, c) __builtin_amdgcn_mfma_f32_16x16x32_bf16((a), (b), (c), 0, 0, 0)

#define GLOAD16(g, l) __builtin_amdgcn_global_load_lds( \
    (const __attribute__((address_space(1))) void*)(g),  \
    (__attribute__((address_space(3))) void*)(l), 16, 0, 0)

__device__ __forceinline__ float bf2f(unsigned short u) {
    unsigned int x = ((unsigned int)u) << 16;
    return __builtin_bit_cast(float, x);
}
__device__ __forceinline__ unsigned short f2bf(float f) {
    unsigned int x = __builtin_bit_cast(unsigned int, f);
    x = x + 0x7FFFu + ((x >> 16) & 1u);
    return (unsigned short)(x >> 16);
}
// dtype flag: fp32 1.0 has low half-word 0x0000; bf16 1.0 is 0x3F80.
__device__ __forceinline__ bool is_f32(const unsigned short* tf) { return tf[0] == 0; }
__device__ __forceinline__ float ldscal(const void* p, int i, bool f32m) {
    return f32m ? ((const float*)p)[i] : bf2f(((const unsigned short*)p)[i]);
}

// ---------------------------------------------------------------------------
// prep_all: blocks [0,12288): dual transpose x -> xb,xbT + fused colsum
//           blocks [12288,13008): weight prep (WqkT / Wv slice / WprojT)
// (sB+beff zeroed via hipMemsetAsync before launch)
// ---------------------------------------------------------------------------
__device__ __forceinline__ void tr_tile(const void* in_, unsigned short* out,
                                        int R, int C, int istride,
                                        int bid, bool f32m, unsigned short* T)
{
    const int nct = C >> 6;
    const int tx = bid % nct;
    const int ty = bid / nct;
    const int r0 = ty * 64, c0 = tx * 64;
    const int t = threadIdx.x;
#pragma unroll
    for (int s = 0; s < 2; ++s) {
        const int idx = t + s * 256;
        const int rr = idx >> 3;
        const int cc = (idx & 7) * 8;
        unsigned short v[8];
        if (f32m) {
            const float* inf = (const float*)in_;
            f32x4 a = *(const f32x4*)&inf[(size_t)(r0 + rr) * istride + c0 + cc];
            f32x4 b = *(const f32x4*)&inf[(size_t)(r0 + rr) * istride + c0 + cc + 4];
#pragma unroll
            for (int j = 0; j < 4; ++j) { v[j] = f2bf(a[j]); v[4 + j] = f2bf(b[j]); }
        } else {
            u16x8 a = *(const u16x8*)&((const unsigned short*)in_)[(size_t)(r0 + rr) * istride + c0 + cc];
#pragma unroll
            for (int j = 0; j < 8; ++j) v[j] = a[j];
        }
#pragma unroll
        for (int j = 0; j < 8; ++j) T[(cc + j) * 72 + rr] = v[j];
    }
    __syncthreads();
#pragma unroll
    for (int s = 0; s < 2; ++s) {
        const int idx = t + s * 256;
        const int cc = idx >> 3;
        const int rr = (idx & 7) * 8;
        u16x8 v = *(const u16x8*)&T[cc * 72 + rr];
        *(u16x8*)&out[(size_t)(c0 + cc) * R + r0 + rr] = v;
    }
}

__global__ __launch_bounds__(256)
void prep_all(const void* __restrict__ x, unsigned short* __restrict__ xb,
              unsigned short* __restrict__ xbT, float* __restrict__ sB,
              const void* __restrict__ Wqkv, const void* __restrict__ Wp,
              unsigned short* __restrict__ WqkT, unsigned short* __restrict__ Wv_bf,
              unsigned short* __restrict__ WprojT, const unsigned short* __restrict__ tf)
{
    __shared__ unsigned short T[64 * 72];
    const bool f32m = is_f32(tf);
    if (blockIdx.x < 12288) {
        const int tx = blockIdx.x % 12;
        const int ty = blockIdx.x / 12;
        const int r0 = ty * 64, c0 = tx * 64;
        const int t = threadIdx.x;
#pragma unroll
        for (int s = 0; s < 2; ++s) {
            const int idx = t + s * 256;
            const int rr = idx >> 3;
            const int cc = (idx & 7) * 8;
            u16x8 v;
            if (f32m) {
                const float* inf = (const float*)x;
                f32x4 a = *(const f32x4*)&inf[(size_t)(r0 + rr) * 768 + c0 + cc];
                f32x4 b = *(const f32x4*)&inf[(size_t)(r0 + rr) * 768 + c0 + cc + 4];
#pragma unroll
                for (int j = 0; j < 4; ++j) { v[j] = f2bf(a[j]); v[4 + j] = f2bf(b[j]); }
            } else {
                v = *(const u16x8*)&((const unsigned short*)x)[(size_t)(r0 + rr) * 768 + c0 + cc];
            }
            *(u16x8*)&xb[(size_t)(r0 + rr) * 768 + c0 + cc] = v;
#pragma unroll
            for (int j = 0; j < 8; ++j) T[(cc + j) * 72 + rr] = v[j];
        }
        __syncthreads();
#pragma unroll
        for (int s = 0; s < 2; ++s) {
            const int idx = t + s * 256;
            const int cc = idx >> 3;
            const int rr = (idx & 7) * 8;
            u16x8 v = *(const u16x8*)&T[cc * 72 + rr];
            *(u16x8*)&xbT[(size_t)(c0 + cc) * 65536 + r0 + rr] = v;
        }
        {
            const int col = t >> 2;
            const int seg = t & 3;
            float s = 0.f;
#pragma unroll
            for (int r = 0; r < 16; ++r) s += bf2f(T[col * 72 + seg * 16 + r]);
            s += __shfl_xor(s, 1);
            s += __shfl_xor(s, 2);
            if (seg == 0) atomicAdd(&sB[(r0 >> 12) * 768 + c0 + col], s);
        }
    } else {
        const int bid = blockIdx.x - 12288;
        if (bid < 288) {
            tr_tile(Wqkv, WqkT, 768, 1536, 2304, bid, f32m, T);
        } else if (bid < 576) {
            const int t = (bid - 288) * 256 + threadIdx.x;
            const int c = t / 96;
            const int e0 = (t % 96) * 8;
            u16x8 v;
            if (f32m) {
                const float* p = (const float*)Wqkv + (size_t)c * 2304 + 1536 + e0;
                f32x4 a = *(const f32x4*)p;
                f32x4 b = *(const f32x4*)(p + 4);
#pragma unroll
                for (int j = 0; j < 4; ++j) { v[j] = f2bf(a[j]); v[4 + j] = f2bf(b[j]); }
            } else {
                v = *(const u16x8*)&((const unsigned short*)Wqkv)[(size_t)c * 2304 + 1536 + e0];
            }
            *(u16x8*)&Wv_bf[(size_t)c * 768 + e0] = v;
        } else {
            tr_tile(Wp, WprojT, 768, 768, 768, bid - 576, f32m, T);
        }
    }
}

// ---------------------------------------------------------------------------
// gemmG: G_b = xb_b^T xb_b, SYMMETRIC (21 of 36 tiles + mirror), validated
// rounds 11-15. 128x128, 4 waves, BK=64 dbuf, vmcnt(8).
// ---------------------------------------------------------------------------
__global__ __launch_bounds__(256, 2)
void gemmG(const unsigned short* __restrict__ A, unsigned short* __restrict__ G)
{
    constexpr int NT = 64;
    constexpr size_t LD = 65536;
    __shared__ __align__(16) char SM[65536];
    unsigned short* lds = (unsigned short*)SM;

    const int tid  = threadIdx.x;
    const int wave = tid >> 6;
    const int lane = tid & 63;
    const int wm   = wave >> 1;
    const int wn   = wave & 1;
    const int lr   = lane & 15;
    const int lq   = lane >> 4;

    const int per = gridDim.x >> 3;
    const int wg  = (blockIdx.x & 7) * per + (blockIdx.x >> 3);
    const int b = wg / 21;
    int rr21 = wg % 21;
    int mt = 0;
    while (rr21 >= 6 - mt) { rr21 -= 6 - mt; ++mt; }
    const int nt = mt + rr21;
    const size_t m0 = (size_t)mt * 128;
    const int n0 = nt * 128;

    const unsigned short* Ab = A + m0 * LD + (size_t)b * 4096;
    const unsigned short* Bb = A + (size_t)n0 * LD + (size_t)b * 4096;
    unsigned short* Gb = G + (size_t)b * 589824;

    f32x4 zero = {0.f, 0.f, 0.f, 0.f};
    f32x4 acc[4][4];
#pragma unroll
    for (int i = 0; i < 4; ++i)
#pragma unroll
        for (int j = 0; j < 4; ++j) acc[i][j] = zero;

    auto STAGE = [&](int t) {
        unsigned short* la_ = lds + (t & 1) * 16384;
        unsigned short* lb_ = la_ + 8192;
#pragma unroll
        for (int it = 0; it < 4; ++it) {
            const int c = it * 256 + tid;
            const int row = c >> 3;
            const int gs = (c & 7) ^ (row & 7);
            GLOAD16(Ab + (size_t)row * LD + t * 64 + gs * 8, la_ + c * 8);
        }
#pragma unroll
        for (int it = 0; it < 4; ++it) {
            const int c = it * 256 + tid;
            const int row = c >> 3;
            const int gs = (c & 7) ^ (row & 7);
            GLOAD16(Bb + (size_t)row * LD + t * 64 + gs * 8, lb_ + c * 8);
        }
    };

    STAGE(0);
    STAGE(1);

    for (int t = 0; t < NT; ++t) {
        if (t + 1 < NT) asm volatile("s_waitcnt vmcnt(8)" ::: "memory");
        else            asm volatile("s_waitcnt vmcnt(0)" ::: "memory");
        __builtin_amdgcn_s_barrier();
        __builtin_amdgcn_sched_barrier(0);

        const char* la = (const char*)(lds + (t & 1) * 16384);
        const char* lb = la + 16384;

        bf16x8 bfr[4][2], af[4][2];
#pragma unroll
        for (int ni = 0; ni < 4; ++ni)
#pragma unroll
            for (int ks = 0; ks < 2; ++ks) {
                const int row = wn * 64 + ni * 16 + lr;
                const int s   = ks * 4 + lq;
                bfr[ni][ks] = *(const bf16x8*)(lb + row * 128 + ((s ^ (row & 7)) << 4));
            }
#pragma unroll
        for (int mi = 0; mi < 4; ++mi)
#pragma unroll
            for (int ks = 0; ks < 2; ++ks) {
                const int row = wm * 64 + mi * 16 + lr;
                const int s   = ks * 4 + lq;
                af[mi][ks] = *(const bf16x8*)(la + row * 128 + ((s ^ (row & 7)) << 4));
            }
        __builtin_amdgcn_s_setprio(1);
#pragma unroll
        for (int mi = 0; mi < 4; ++mi)
#pragma unroll
            for (int ni = 0; ni < 4; ++ni)
#pragma unroll
                for (int ks = 0; ks < 2; ++ks)
                    acc[mi][ni] = MFMA16(af[mi][ks], bfr[ni][ks], acc[mi][ni]);
        __builtin_amdgcn_s_setprio(0);

        __builtin_amdgcn_sched_barrier(0);
        __builtin_amdgcn_s_barrier();
        if (t + 2 < NT) STAGE(t + 2);
    }

#pragma unroll
    for (int mi = 0; mi < 4; ++mi)
#pragma unroll
        for (int ni = 0; ni < 4; ++ni)
#pragma unroll
            for (int r = 0; r < 4; ++r) {
                const size_t row = m0 + (size_t)(wm * 64 + mi * 16 + lq * 4 + r);
                const int col = n0 + wn * 64 + ni * 16 + lr;
                Gb[row * 768 + col] = f2bf(acc[mi][ni][r]);
            }

    if (mt != nt) {
        asm volatile("s_waitcnt lgkmcnt(0)" ::: "memory");
        __builtin_amdgcn_s_barrier();
        unsigned short* CTw = (unsigned short*)SM + wave * (64 * 68);
#pragma unroll
        for (int mi = 0; mi < 4; ++mi)
#pragma unroll
            for (int ni = 0; ni < 4; ++ni) {
                u16x4 pk;
#pragma unroll
                for (int r = 0; r < 4; ++r) pk[r] = f2bf(acc[mi][ni][r]);
                *(u16x4*)&CTw[(ni * 16 + lr) * 68 + mi * 16 + lq * 4] = pk;
            }
#pragma unroll
        for (int rep = 0; rep < 8; ++rep) {
            const int idx = rep * 64 + lane;
            const int c = idx >> 3;
            const int j = (idx & 7) * 8;
            u16x8 v = *(const u16x8*)&CTw[c * 68 + j];
            const size_t rowT = (size_t)n0 + wn * 64 + c;
            const int colT = (int)m0 + wm * 64 + j;
            *(u16x8*)&Gb[rowT * 768 + colT] = v;
        }
    }
}

// ---------------------------------------------------------------------------
// gemmH: 128x256 tile, BK=32, 8 waves, TRIPLE-buffered LDS (72KB), single
// barrier per K-step (validated r14/r15 ledger: vmcnt(3) steady / 0 tail).
// f32 epilogue (MODE 1): LDS repack -> coalesced f32x4 stores (r15, +13%).
// bf16 epilogues (MODE 2/4 and MODE1-bf16): LDS repack -> u16x8 stores (NEW).
// MODE 1: out = xb @ PT_b + beff_b + bp   (grid 1536)
// MODE 2: PT  = MbT @ Wv                  (grid 288)
// MODE 4: P_b = WqkT @ G_b                (grid 576)
// ---------------------------------------------------------------------------
template<int MODE>
__global__ __launch_bounds__(512, 4)
void gemmH(const unsigned short* __restrict__ A,
           const unsigned short* __restrict__ BT,
           const float* __restrict__ bias,
           const void* __restrict__ bp,
           unsigned short* __restrict__ o0,
           float* __restrict__ oF,
           const unsigned short* __restrict__ tf)
{
    constexpr int K = 768, NT = 24;
    __shared__ __align__(16) char SM[73728];   // 3 bufs x (A 8KB + B 16KB)

    const bool f32m = is_f32(tf);
    const int tid  = threadIdx.x;
    const int wave = tid >> 6;
    const int lane = tid & 63;
    const int wm   = wave >> 2;
    const int wn   = wave & 3;
    const int lr   = lane & 15;
    const int lq   = lane >> 4;

    const int per = gridDim.x >> 3;
    const int wg  = (blockIdx.x & 7) * per + (blockIdx.x >> 3);
    int b = 0, mt, nt;
    if (MODE == 4) { b = wg / 36; const int r = wg % 36; mt = r / 3; nt = r % 3; }
    else           { mt = wg / 3; nt = wg % 3; }
    const size_t m0 = (size_t)mt * 128;
    const int n0 = nt * 256;

    const unsigned short* Ab = A + m0 * K;
    const unsigned short* Bb;
    if (MODE == 1)      Bb = BT + (m0 >> 12) * (size_t)589824 + (size_t)n0 * K;
    else if (MODE == 4) Bb = BT + (size_t)b * 589824 + (size_t)n0 * K;
    else                Bb = BT + (size_t)n0 * K;

    f32x4 zero = {0.f, 0.f, 0.f, 0.f};
    f32x4 acc[4][4];
#pragma unroll
    for (int i = 0; i < 4; ++i)
#pragma unroll
        for (int j = 0; j < 4; ++j) acc[i][j] = zero;

    auto STAGE = [&](int t) {
        char* base = SM + (t % 3) * 24576;
        {
            const int c = tid;                        // A: 128x32
            const int rp = c >> 3;
            const int ch = (c & 7) ^ (rp & 7);
            const int srow = rp * 2 + (ch >> 2);
            const int sk = (ch & 3) * 8;
            GLOAD16(Ab + (size_t)srow * K + t * 32 + sk, base + c * 16);
        }
#pragma unroll
        for (int ev = 0; ev < 2; ++ev) {
            const int c = ev * 512 + tid;             // B: 256x32
            const int rp = c >> 3;
            const int ch = (c & 7) ^ (rp & 7);
            const int srow = rp * 2 + (ch >> 2);
            const int sk = (ch & 3) * 8;
            GLOAD16(Bb + (size_t)srow * K + t * 32 + sk, base + 8192 + c * 16);
        }
    };

    STAGE(0);
    STAGE(1);

    for (int t = 0; t < NT; ++t) {
        if (t < NT - 1) asm volatile("s_waitcnt vmcnt(3)" ::: "memory");
        else            asm volatile("s_waitcnt vmcnt(0)" ::: "memory");
        __builtin_amdgcn_s_barrier();
        __builtin_amdgcn_sched_barrier(0);

        const char* la = SM + (t % 3) * 24576;
        const char* lb = la + 8192;

        bf16x8 af[4], bfr[4];
#pragma unroll
        for (int ni = 0; ni < 4; ++ni) {
            const int row = wn * 64 + ni * 16 + lr;
            const int rp = row >> 1;
            const int ch = (row & 1) * 4 + lq;
            bfr[ni] = *(const bf16x8*)(lb + rp * 128 + ((ch ^ (rp & 7)) << 4));
        }
#pragma unroll
        for (int mi = 0; mi < 4; ++mi) {
            const int row = wm * 64 + mi * 16 + lr;
            const int rp = row >> 1;
            const int ch = (row & 1) * 4 + lq;
            af[mi] = *(const bf16x8*)(la + rp * 128 + ((ch ^ (rp & 7)) << 4));
        }
        __builtin_amdgcn_s_setprio(1);
#pragma unroll
        for (int mi = 0; mi < 4; ++mi)
#pragma unroll
            for (int ni = 0; ni < 4; ++ni)
                acc[mi][ni] = MFMA16(af[mi], bfr[ni], acc[mi][ni]);
        __builtin_amdgcn_s_setprio(0);

        __builtin_amdgcn_sched_barrier(0);
        if (t + 2 < NT) STAGE(t + 2);
    }

    float bb[4];
#pragma unroll
    for (int ni = 0; ni < 4; ++ni) {
        const int col = n0 + wn * 64 + ni * 16 + lr;
        bb[ni] = (MODE == 1) ? (bias[(m0 >> 12) * 768 + col] + ldscal(bp, col, f32m)) : 0.f;
    }

    // drain K-loop LDS reads, then reuse LDS for epilogue repack
    asm volatile("s_waitcnt lgkmcnt(0)" ::: "memory");
    __builtin_amdgcn_s_barrier();

    if (MODE == 1 && f32m) {
        float* Lf = (float*)SM + wave * 2176;        // 32 rows x 68 f32
#pragma unroll
        for (int mh = 0; mh < 2; ++mh) {
#pragma unroll
            for (int mp = 0; mp < 2; ++mp)
#pragma unroll
                for (int ni = 0; ni < 4; ++ni)
#pragma unroll
                    for (int r = 0; r < 4; ++r) {
                        const int lrow = mp * 16 + lq * 4 + r;
                        const int lcol = ni * 16 + lr;
                        Lf[lrow * 68 + lcol] = acc[mh * 2 + mp][ni][r] + bb[ni];
                    }
#pragma unroll
            for (int rr = 0; rr < 8; ++rr) {
                const int lrow = rr * 4 + lq;
                const int lcol = lr * 4;
                f32x4 v = *(const f32x4*)&Lf[lrow * 68 + lcol];
                const size_t grow = m0 + (size_t)(wm * 64 + mh * 32 + lrow);
                *(f32x4*)&oF[grow * 768 + n0 + wn * 64 + lcol] = v;
            }
        }
    } else {
        // bf16 coalesced store: repack 64x64 wave tile via LDS, u16x8 stores
        unsigned short* Lh = (unsigned short*)SM + wave * 2304;   // 32 x 72 u16
#pragma unroll
        for (int mh = 0; mh < 2; ++mh) {
#pragma unroll
            for (int mp = 0; mp < 2; ++mp)
#pragma unroll
                for (int ni = 0; ni < 4; ++ni)
#pragma unroll
                    for (int r = 0; r < 4; ++r) {
                        const int lrow = mp * 16 + lq * 4 + r;
                        const int lcol = ni * 16 + lr;
                        Lh[lrow * 72 + lcol] = f2bf(acc[mh * 2 + mp][ni][r] + bb[ni]);
                    }
#pragma unroll
            for (int rr = 0; rr < 4; ++rr) {
                const int lrow = rr * 8 + (lane >> 3);
                const int lcol = (lane & 7) * 8;
                u16x8 v = *(const u16x8*)&Lh[lrow * 72 + lcol];
                const size_t grow = m0 + (size_t)(wm * 64 + mh * 32 + lrow);
                const int gcol = n0 + wn * 64 + lcol;
                if (MODE == 4)
                    *(u16x8*)&o0[(size_t)b * 1179648 + grow * 768 + gcol] = v;
                else
                    *(u16x8*)&o0[grow * 768 + gcol] = v;
            }
        }
    }
}

// ---------------------------------------------------------------------------
// attn_mb: fused attn + mb_build + beff partials (validated r14/r15).
// ---------------------------------------------------------------------------
__global__ __launch_bounds__(512)
void attn_mb(const unsigned short* __restrict__ P,
             const unsigned short* __restrict__ WqkT,
             const float* __restrict__ s,
             const void* __restrict__ bqkv,
             const unsigned short* __restrict__ WprojT,
             const unsigned short* __restrict__ tf,
             unsigned short* __restrict__ MbT,
             float* __restrict__ beff)
{
    __shared__ float S[64][64];
    __shared__ float nq[64], nk[64], uq[64], uk[64];
    __shared__ float sb[768];
    __shared__ float bkv[64];
    __shared__ float bvv[64];
    __shared__ unsigned short Pl[64 * 72];
    const bool f32m = is_f32(tf);
    const int bh = blockIdx.x;
    const int b = bh / 12, h = bh % 12;
    const unsigned short* Pq = P + (size_t)b * 1179648 + (size_t)(h * 64) * 768;
    const unsigned short* Wq = WqkT + (size_t)(h * 64) * 768;
    const unsigned short* Pk = Pq + 589824;
    const unsigned short* Wk = Wq + 589824;
    const int tid = threadIdx.x;
    const int wave = tid >> 6;
    const int lane = tid & 63;
    const int lr = lane & 15;
    const int lq = lane >> 4;

    for (int i = tid; i < 768; i += 512) sb[i] = s[b * 768 + i];
    if (tid < 64)       bkv[tid] = ldscal(bqkv, 768 + h * 64 + tid, f32m);
    else if (tid < 128) bvv[tid - 64] = ldscal(bqkv, 1536 + h * 64 + (tid - 64), f32m);

    f32x4 zero = {0.f, 0.f, 0.f, 0.f};
    f32x4 acc[4][4];
#pragma unroll
    for (int i = 0; i < 4; ++i)
#pragma unroll
        for (int j = 0; j < 4; ++j) acc[i][j] = zero;

    for (int ks = 0; ks < 3; ++ks) {
        const int j0 = wave * 96 + ks * 32 + lq * 8;
        u16x8 qa[4], ka[4];
#pragma unroll
        for (int mi = 0; mi < 4; ++mi)
            qa[mi] = *(const u16x8*)&Pq[(size_t)(mi * 16 + lr) * 768 + j0];
#pragma unroll
        for (int ni = 0; ni < 4; ++ni)
            ka[ni] = *(const u16x8*)&Wk[(size_t)(ni * 16 + lr) * 768 + j0];
#pragma unroll
        for (int mi = 0; mi < 4; ++mi)
#pragma unroll
            for (int ni = 0; ni < 4; ++ni)
                acc[mi][ni] = MFMA16(__builtin_bit_cast(bf16x8, qa[mi]),
                                     __builtin_bit_cast(bf16x8, ka[ni]),
                                     acc[mi][ni]);
    }
    __syncthreads();

    for (int ww = 0; ww < 8; ++ww) {
        if (wave == ww) {
#pragma unroll
            for (int mi = 0; mi < 4; ++mi)
#pragma unroll
                for (int ni = 0; ni < 4; ++ni)
#pragma unroll
                    for (int r = 0; r < 4; ++r) {
                        const int d = mi * 16 + lq * 4 + r;
                        const int e = ni * 16 + lr;
                        if (ww == 0) S[d][e] = acc[mi][ni][r];
                        else         S[d][e] += acc[mi][ni][r];
                    }
        }
        __syncthreads();
    }

    const int d   = tid >> 3;
    const int oct = tid & 7;
    {
        const unsigned short* pqr = Pq + (size_t)d * 768 + oct * 96;
        const unsigned short* wqr = Wq + (size_t)d * 768 + oct * 96;
        const unsigned short* pkr = Pk + (size_t)d * 768 + oct * 96;
        const unsigned short* wkr = Wk + (size_t)d * 768 + oct * 96;
        float a_nq = 0.f, a_uq = 0.f, a_nk = 0.f, a_uk = 0.f;
        for (int i = 0; i < 12; ++i) {
            u16x8 vp = *(const u16x8*)&pqr[i * 8];
            u16x8 vw = *(const u16x8*)&wqr[i * 8];
            u16x8 kp = *(const u16x8*)&pkr[i * 8];
            u16x8 kw = *(const u16x8*)&wkr[i * 8];
#pragma unroll
            for (int j = 0; j < 8; ++j) {
                const float wqv = bf2f(vw[j]);
                const float wkv = bf2f(kw[j]);
                const float sj = sb[oct * 96 + i * 8 + j];
                a_nq += bf2f(vp[j]) * wqv;
                a_uq += sj * wqv;
                a_nk += bf2f(kp[j]) * wkv;
                a_uk += sj * wkv;
            }
        }
        a_nq += __shfl_xor(a_nq, 1); a_nq += __shfl_xor(a_nq, 2); a_nq += __shfl_xor(a_nq, 4);
        a_uq += __shfl_xor(a_uq, 1); a_uq += __shfl_xor(a_uq, 2); a_uq += __shfl_xor(a_uq, 4);
        a_nk += __shfl_xor(a_nk, 1); a_nk += __shfl_xor(a_nk, 2); a_nk += __shfl_xor(a_nk, 4);
        a_uk += __shfl_xor(a_uk, 1); a_uk += __shfl_xor(a_uk, 2); a_uk += __shfl_xor(a_uk, 4);
        if (oct == 0) { nq[d] = a_nq; uq[d] = a_uq; nk[d] = a_nk; uk[d] = a_uk; }
    }
    __syncthreads();

    {
        const float tv  = f32m ? ((const float*)tf)[h] : bf2f(tf[h]);
        const float bqd = ldscal(bqkv, h * 64 + d, f32m);
        const float uqd = uq[d];
        const float nqf = nq[d] + 2.f * bqd * uqd + 4096.f * bqd * bqd;
        const float qn  = fmaxf(sqrtf(fmaxf(nqf, 0.f)), 1e-12f);
        float vals[8];
        float mx = -1e30f;
#pragma unroll
        for (int i = 0; i < 8; ++i) {
            const int e = oct * 8 + i;
            const float bke = bkv[e];
            const float nkf = nk[e] + 2.f * bke * uk[e] + 4096.f * bke * bke;
            const float kn  = fmaxf(sqrtf(fmaxf(nkf, 0.f)), 1e-12f);
            const float sv  = S[d][e] + bqd * uk[e] + uqd * bke + 4096.f * bqd * bke;
            const float val = sv / (qn * kn) * tv;
            vals[i] = val;
            mx = fmaxf(mx, val);
        }
        mx = fmaxf(mx, __shfl_xor(mx, 1));
        mx = fmaxf(mx, __shfl_xor(mx, 2));
        mx = fmaxf(mx, __shfl_xor(mx, 4));
        float sum = 0.f;
#pragma unroll
        for (int i = 0; i < 8; ++i) { vals[i] = __expf(vals[i] - mx); sum += vals[i]; }
        sum += __shfl_xor(sum, 1);
        sum += __shfl_xor(sum, 2);
        sum += __shfl_xor(sum, 4);
        const float inv = 1.0f / sum;
#pragma unroll
        for (int i = 0; i < 8; ++i) {
            const int e = oct * 8 + i;
            Pl[e * 72 + d] = f2bf(vals[i] * inv);
        }
    }
    __syncthreads();

    f32x4 accm[4][6];
#pragma unroll
    for (int i = 0; i < 4; ++i)
#pragma unroll
        for (int j = 0; j < 6; ++j) accm[i][j] = zero;

#pragma unroll
    for (int ks = 0; ks < 2; ++ks) {
        bf16x8 af[4], bfr[6];
#pragma unroll
        for (int mi = 0; mi < 4; ++mi)
            af[mi] = *(const bf16x8*)&Pl[(mi * 16 + lr) * 72 + ks * 32 + lq * 8];
#pragma unroll
        for (int ni = 0; ni < 6; ++ni) {
            const int j = wave * 96 + ni * 16 + lr;
            bfr[ni] = *(const bf16x8*)&WprojT[(size_t)j * 768 + h * 64 + ks * 32 + lq * 8];
        }
#pragma unroll
        for (int mi = 0; mi < 4; ++mi)
#pragma unroll
            for (int ni = 0; ni < 6; ++ni)
                accm[mi][ni] = MFMA16(af[mi], bfr[ni], accm[mi][ni]);
    }

#pragma unroll
    for (int ni = 0; ni < 6; ++ni) {
        const int j = wave * 96 + ni * 16 + lr;
        float part = 0.f;
#pragma unroll
        for (int mi = 0; mi < 4; ++mi) {
            const int e = mi * 16 + lq * 4;
            u16x4 pk;
#pragma unroll
            for (int r = 0; r < 4; ++r) {
                pk[r] = f2bf(accm[mi][ni][r]);
                part += accm[mi][ni][r] * bvv[e + r];
            }
            *(u16x4*)&MbT[(size_t)b * 589824 + (size_t)j * 768 + h * 64 + e] = pk;
        }
        atomicAdd(&beff[b * 768 + j], part);
    }
}

// ---------------------------------------------------------------------------
extern "C" void kernel_launch(void* const* d_in, const int* in_sizes, int n_in,
                              void* d_out, int out_size, void* d_ws, size_t ws_size,
                              hipStream_t stream)
{
    const void* x    = d_in[0];
    const void* Wqkv = d_in[1];
    const void* bqkv = d_in[2];
    const void* Wp   = d_in[3];
    const void* bp   = d_in[4];
    const unsigned short* tf = (const unsigned short*)d_in[5];

    char* w = (char*)d_ws;
    unsigned short* xbT    = (unsigned short*)(w);                  // [768][65536]
    unsigned short* xb     = (unsigned short*)(w + 100663296);      // [65536][768]
    unsigned short* G      = (unsigned short*)(w + 201326592);      // [16][768][768]
    unsigned short* P      = (unsigned short*)(w + 220200960);      // [16][1536][768]
    unsigned short* PT     = (unsigned short*)(w + 257949696);      // [16][768][768]
    unsigned short* MbT    = (unsigned short*)(w + 276824064);      // [16][768][768]
    unsigned short* WqkT   = (unsigned short*)(w + 295698432);      // [1536][768]
    unsigned short* Wv_bf  = (unsigned short*)(w + 298057728);      // [768][768]
    unsigned short* WprojT = (unsigned short*)(w + 299237376);      // [768][768]
    float*          sB     = (float*)(w + 301989888);               // [16][768]
    float*          beff   = (float*)(w + 302039040);               // [16][768]
    // total ws use: 302088192 B

    hipMemsetAsync(sB, 0, 98304, stream);   // sB + beff (adjacent)
    prep_all<<<dim3(13008), dim3(256), 0, stream>>>(x, xb, xbT, sB, Wqkv, Wp,
                                                    WqkT, Wv_bf, WprojT, tf);

    gemmG<<<dim3(336), dim3(256), 0, stream>>>(xbT, G);
    gemmH<4><<<dim3(576), dim3(512), 0, stream>>>(WqkT, G, nullptr, nullptr, P, nullptr, tf);
    attn_mb<<<dim3(192), dim3(512), 0, stream>>>(P, WqkT, sB, bqkv, WprojT, tf, MbT, beff);
    gemmH<2><<<dim3(288), dim3(512), 0, stream>>>(MbT, Wv_bf, nullptr, nullptr, PT, nullptr, tf);
    gemmH<1><<<dim3(1536), dim3(512), 0, stream>>>(xb, PT, beff, bp,
        (unsigned short*)d_out, (float*)d_out, tf);
}

// Round 18
// 403.134 us; speedup vs baseline: 1.1340x; 1.0043x over previous
//
#include <hip/hip_runtime.h>

typedef __bf16 bf16x8 __attribute__((ext_vector_type(8)));
typedef float  f32x4  __attribute__((ext_vector_type(4)));
typedef unsigned short u16x8 __attribute__((ext_vector_type(8)));
typedef unsigned short u16x4 __attribute__((ext_vector_type(4)));

#define MFMA16(a, b, c) __builtin_amdgcn_mfma_f32_16x16x32_bf16((a), (b), (c), 0, 0, 0)

#define GLOAD16(g, l) __builtin_amdgcn_global_load_lds( \
    (const __attribute__((address_space(1))) void*)(g),  \
    (__attribute__((address_space(3))) void*)(l), 16, 0, 0)

__device__ __forceinline__ float bf2f(unsigned short u) {
    unsigned int x = ((unsigned int)u) << 16;
    return __builtin_bit_cast(float, x);
}
__device__ __forceinline__ unsigned short f2bf(float f) {
    unsigned int x = __builtin_bit_cast(unsigned int, f);
    x = x + 0x7FFFu + ((x >> 16) & 1u);
    return (unsigned short)(x >> 16);
}
// dtype flag: fp32 1.0 has low half-word 0x0000; bf16 1.0 is 0x3F80.
__device__ __forceinline__ bool is_f32(const unsigned short* tf) { return tf[0] == 0; }
__device__ __forceinline__ float ldscal(const void* p, int i, bool f32m) {
    return f32m ? ((const float*)p)[i] : bf2f(((const unsigned short*)p)[i]);
}

// ---------------------------------------------------------------------------
// prep_all: blocks [0,12288): dual transpose x -> xb,xbT + fused colsum
//           blocks [12288,13008): weight prep (WqkT / Wv slice / WprojT)
// (sB+beff zeroed via hipMemsetAsync before launch)
// ---------------------------------------------------------------------------
__device__ __forceinline__ void tr_tile(const void* in_, unsigned short* out,
                                        int R, int C, int istride,
                                        int bid, bool f32m, unsigned short* T)
{
    const int nct = C >> 6;
    const int tx = bid % nct;
    const int ty = bid / nct;
    const int r0 = ty * 64, c0 = tx * 64;
    const int t = threadIdx.x;
#pragma unroll
    for (int s = 0; s < 2; ++s) {
        const int idx = t + s * 256;
        const int rr = idx >> 3;
        const int cc = (idx & 7) * 8;
        unsigned short v[8];
        if (f32m) {
            const float* inf = (const float*)in_;
            f32x4 a = *(const f32x4*)&inf[(size_t)(r0 + rr) * istride + c0 + cc];
            f32x4 b = *(const f32x4*)&inf[(size_t)(r0 + rr) * istride + c0 + cc + 4];
#pragma unroll
            for (int j = 0; j < 4; ++j) { v[j] = f2bf(a[j]); v[4 + j] = f2bf(b[j]); }
        } else {
            u16x8 a = *(const u16x8*)&((const unsigned short*)in_)[(size_t)(r0 + rr) * istride + c0 + cc];
#pragma unroll
            for (int j = 0; j < 8; ++j) v[j] = a[j];
        }
#pragma unroll
        for (int j = 0; j < 8; ++j) T[(cc + j) * 72 + rr] = v[j];
    }
    __syncthreads();
#pragma unroll
    for (int s = 0; s < 2; ++s) {
        const int idx = t + s * 256;
        const int cc = idx >> 3;
        const int rr = (idx & 7) * 8;
        u16x8 v = *(const u16x8*)&T[cc * 72 + rr];
        *(u16x8*)&out[(size_t)(c0 + cc) * R + r0 + rr] = v;
    }
}

__global__ __launch_bounds__(256)
void prep_all(const void* __restrict__ x, unsigned short* __restrict__ xb,
              unsigned short* __restrict__ xbT, float* __restrict__ sB,
              const void* __restrict__ Wqkv, const void* __restrict__ Wp,
              unsigned short* __restrict__ WqkT, unsigned short* __restrict__ Wv_bf,
              unsigned short* __restrict__ WprojT, const unsigned short* __restrict__ tf)
{
    __shared__ unsigned short T[64 * 72];
    const bool f32m = is_f32(tf);
    if (blockIdx.x < 12288) {
        const int tx = blockIdx.x % 12;
        const int ty = blockIdx.x / 12;
        const int r0 = ty * 64, c0 = tx * 64;
        const int t = threadIdx.x;
#pragma unroll
        for (int s = 0; s < 2; ++s) {
            const int idx = t + s * 256;
            const int rr = idx >> 3;
            const int cc = (idx & 7) * 8;
            u16x8 v;
            if (f32m) {
                const float* inf = (const float*)x;
                f32x4 a = *(const f32x4*)&inf[(size_t)(r0 + rr) * 768 + c0 + cc];
                f32x4 b = *(const f32x4*)&inf[(size_t)(r0 + rr) * 768 + c0 + cc + 4];
#pragma unroll
                for (int j = 0; j < 4; ++j) { v[j] = f2bf(a[j]); v[4 + j] = f2bf(b[j]); }
            } else {
                v = *(const u16x8*)&((const unsigned short*)x)[(size_t)(r0 + rr) * 768 + c0 + cc];
            }
            *(u16x8*)&xb[(size_t)(r0 + rr) * 768 + c0 + cc] = v;
#pragma unroll
            for (int j = 0; j < 8; ++j) T[(cc + j) * 72 + rr] = v[j];
        }
        __syncthreads();
#pragma unroll
        for (int s = 0; s < 2; ++s) {
            const int idx = t + s * 256;
            const int cc = idx >> 3;
            const int rr = (idx & 7) * 8;
            u16x8 v = *(const u16x8*)&T[cc * 72 + rr];
            *(u16x8*)&xbT[(size_t)(c0 + cc) * 65536 + r0 + rr] = v;
        }
        {
            const int col = t >> 2;
            const int seg = t & 3;
            float s = 0.f;
#pragma unroll
            for (int r = 0; r < 16; ++r) s += bf2f(T[col * 72 + seg * 16 + r]);
            s += __shfl_xor(s, 1);
            s += __shfl_xor(s, 2);
            if (seg == 0) atomicAdd(&sB[(r0 >> 12) * 768 + c0 + col], s);
        }
    } else {
        const int bid = blockIdx.x - 12288;
        if (bid < 288) {
            tr_tile(Wqkv, WqkT, 768, 1536, 2304, bid, f32m, T);
        } else if (bid < 576) {
            const int t = (bid - 288) * 256 + threadIdx.x;
            const int c = t / 96;
            const int e0 = (t % 96) * 8;
            u16x8 v;
            if (f32m) {
                const float* p = (const float*)Wqkv + (size_t)c * 2304 + 1536 + e0;
                f32x4 a = *(const f32x4*)p;
                f32x4 b = *(const f32x4*)(p + 4);
#pragma unroll
                for (int j = 0; j < 4; ++j) { v[j] = f2bf(a[j]); v[4 + j] = f2bf(b[j]); }
            } else {
                v = *(const u16x8*)&((const unsigned short*)Wqkv)[(size_t)c * 2304 + 1536 + e0];
            }
            *(u16x8*)&Wv_bf[(size_t)c * 768 + e0] = v;
        } else {
            tr_tile(Wp, WprojT, 768, 768, 768, bid - 576, f32m, T);
        }
    }
}

// ---------------------------------------------------------------------------
// gemmG: G_b = xb_b^T xb_b, SYMMETRIC (21 of 36 tiles + mirror), validated
// rounds 11-17. 128x128, 4 waves, BK=64 dbuf, vmcnt(8).
// NEW (r18): both epilogue tiles store coalesced u16x8 via per-wave LDS repack.
// ---------------------------------------------------------------------------
__global__ __launch_bounds__(256, 2)
void gemmG(const unsigned short* __restrict__ A, unsigned short* __restrict__ G)
{
    constexpr int NT = 64;
    constexpr size_t LD = 65536;
    __shared__ __align__(16) char SM[65536];
    unsigned short* lds = (unsigned short*)SM;

    const int tid  = threadIdx.x;
    const int wave = tid >> 6;
    const int lane = tid & 63;
    const int wm   = wave >> 1;
    const int wn   = wave & 1;
    const int lr   = lane & 15;
    const int lq   = lane >> 4;

    const int per = gridDim.x >> 3;
    const int wg  = (blockIdx.x & 7) * per + (blockIdx.x >> 3);
    const int b = wg / 21;
    int rr21 = wg % 21;
    int mt = 0;
    while (rr21 >= 6 - mt) { rr21 -= 6 - mt; ++mt; }
    const int nt = mt + rr21;
    const size_t m0 = (size_t)mt * 128;
    const int n0 = nt * 128;

    const unsigned short* Ab = A + m0 * LD + (size_t)b * 4096;
    const unsigned short* Bb = A + (size_t)n0 * LD + (size_t)b * 4096;
    unsigned short* Gb = G + (size_t)b * 589824;

    f32x4 zero = {0.f, 0.f, 0.f, 0.f};
    f32x4 acc[4][4];
#pragma unroll
    for (int i = 0; i < 4; ++i)
#pragma unroll
        for (int j = 0; j < 4; ++j) acc[i][j] = zero;

    auto STAGE = [&](int t) {
        unsigned short* la_ = lds + (t & 1) * 16384;
        unsigned short* lb_ = la_ + 8192;
#pragma unroll
        for (int it = 0; it < 4; ++it) {
            const int c = it * 256 + tid;
            const int row = c >> 3;
            const int gs = (c & 7) ^ (row & 7);
            GLOAD16(Ab + (size_t)row * LD + t * 64 + gs * 8, la_ + c * 8);
        }
#pragma unroll
        for (int it = 0; it < 4; ++it) {
            const int c = it * 256 + tid;
            const int row = c >> 3;
            const int gs = (c & 7) ^ (row & 7);
            GLOAD16(Bb + (size_t)row * LD + t * 64 + gs * 8, lb_ + c * 8);
        }
    };

    STAGE(0);
    STAGE(1);

    for (int t = 0; t < NT; ++t) {
        if (t + 1 < NT) asm volatile("s_waitcnt vmcnt(8)" ::: "memory");
        else            asm volatile("s_waitcnt vmcnt(0)" ::: "memory");
        __builtin_amdgcn_s_barrier();
        __builtin_amdgcn_sched_barrier(0);

        const char* la = (const char*)(lds + (t & 1) * 16384);
        const char* lb = la + 16384;

        bf16x8 bfr[4][2], af[4][2];
#pragma unroll
        for (int ni = 0; ni < 4; ++ni)
#pragma unroll
            for (int ks = 0; ks < 2; ++ks) {
                const int row = wn * 64 + ni * 16 + lr;
                const int s   = ks * 4 + lq;
                bfr[ni][ks] = *(const bf16x8*)(lb + row * 128 + ((s ^ (row & 7)) << 4));
            }
#pragma unroll
        for (int mi = 0; mi < 4; ++mi)
#pragma unroll
            for (int ks = 0; ks < 2; ++ks) {
                const int row = wm * 64 + mi * 16 + lr;
                const int s   = ks * 4 + lq;
                af[mi][ks] = *(const bf16x8*)(la + row * 128 + ((s ^ (row & 7)) << 4));
            }
        __builtin_amdgcn_s_setprio(1);
#pragma unroll
        for (int mi = 0; mi < 4; ++mi)
#pragma unroll
            for (int ni = 0; ni < 4; ++ni)
#pragma unroll
                for (int ks = 0; ks < 2; ++ks)
                    acc[mi][ni] = MFMA16(af[mi][ks], bfr[ni][ks], acc[mi][ni]);
        __builtin_amdgcn_s_setprio(0);

        __builtin_amdgcn_sched_barrier(0);
        __builtin_amdgcn_s_barrier();
        if (t + 2 < NT) STAGE(t + 2);
    }

    // drain K-loop LDS reads; reuse LDS for epilogue repack
    asm volatile("s_waitcnt lgkmcnt(0)" ::: "memory");
    __builtin_amdgcn_s_barrier();
    unsigned short* Lw = (unsigned short*)SM + wave * (64 * 72);

    // normal tile: repack [row][col] -> coalesced u16x8 stores
#pragma unroll
    for (int mi = 0; mi < 4; ++mi)
#pragma unroll
        for (int ni = 0; ni < 4; ++ni) {
            u16x4 pk;
#pragma unroll
            for (int r = 0; r < 4; ++r) pk[r] = f2bf(acc[mi][ni][r]);
            *(u16x4*)&Lw[(mi * 16 + lq * 4 + 0) * 72 + ni * 16 + lr] = pk;   // placeholder
        }
    // NOTE: u16x4 above packs r=0..3 along columns? No — repack per element:
    // (rewritten correctly below)
    __builtin_amdgcn_sched_barrier(0);
#pragma unroll
    for (int mi = 0; mi < 4; ++mi)
#pragma unroll
        for (int ni = 0; ni < 4; ++ni)
#pragma unroll
            for (int r = 0; r < 4; ++r)
                Lw[(mi * 16 + lq * 4 + r) * 72 + ni * 16 + lr] = f2bf(acc[mi][ni][r]);
#pragma unroll
    for (int rep = 0; rep < 8; ++rep) {
        const int idx = rep * 64 + lane;
        const int lrow = idx >> 3;
        const int lcol = (idx & 7) * 8;
        u16x8 v = *(const u16x8*)&Lw[lrow * 72 + lcol];
        *(u16x8*)&Gb[(m0 + (size_t)(wm * 64 + lrow)) * 768 + n0 + wn * 64 + lcol] = v;
    }

    if (mt != nt) {
        // mirror tile: transposed repack (per-wave private region, in-wave order)
#pragma unroll
        for (int mi = 0; mi < 4; ++mi)
#pragma unroll
            for (int ni = 0; ni < 4; ++ni) {
                u16x4 pk;
#pragma unroll
                for (int r = 0; r < 4; ++r) pk[r] = f2bf(acc[mi][ni][r]);
                *(u16x4*)&Lw[(ni * 16 + lr) * 72 + mi * 16 + lq * 4] = pk;
            }
#pragma unroll
        for (int rep = 0; rep < 8; ++rep) {
            const int idx = rep * 64 + lane;
            const int c = idx >> 3;
            const int j = (idx & 7) * 8;
            u16x8 v = *(const u16x8*)&Lw[c * 72 + j];
            const size_t rowT = (size_t)n0 + wn * 64 + c;
            const int colT = (int)m0 + wm * 64 + j;
            *(u16x8*)&Gb[rowT * 768 + colT] = v;
        }
    }
}

// ---------------------------------------------------------------------------
// gemmH: 128x256 tile, BK=32, 8 waves, TRIPLE-buffered LDS (72KB), single
// barrier per K-step (validated r14/r15 ledger: vmcnt(3) steady / 0 tail).
// Epilogues: LDS repack -> coalesced stores; d_out (MODE 1) uses
// NON-TEMPORAL stores (never re-read; keeps L2 for operand panels).
// MODE 1: out = xb @ PT_b + beff_b + bp   (grid 1536)
// MODE 2: PT  = MbT @ Wv                  (grid 288)
// MODE 4: P_b = WqkT @ G_b                (grid 576)
// ---------------------------------------------------------------------------
template<int MODE>
__global__ __launch_bounds__(512, 4)
void gemmH(const unsigned short* __restrict__ A,
           const unsigned short* __restrict__ BT,
           const float* __restrict__ bias,
           const void* __restrict__ bp,
           unsigned short* __restrict__ o0,
           float* __restrict__ oF,
           const unsigned short* __restrict__ tf)
{
    constexpr int K = 768, NT = 24;
    __shared__ __align__(16) char SM[73728];   // 3 bufs x (A 8KB + B 16KB)

    const bool f32m = is_f32(tf);
    const int tid  = threadIdx.x;
    const int wave = tid >> 6;
    const int lane = tid & 63;
    const int wm   = wave >> 2;
    const int wn   = wave & 3;
    const int lr   = lane & 15;
    const int lq   = lane >> 4;

    const int per = gridDim.x >> 3;
    const int wg  = (blockIdx.x & 7) * per + (blockIdx.x >> 3);
    int b = 0, mt, nt;
    if (MODE == 4) { b = wg / 36; const int r = wg % 36; mt = r / 3; nt = r % 3; }
    else           { mt = wg / 3; nt = wg % 3; }
    const size_t m0 = (size_t)mt * 128;
    const int n0 = nt * 256;

    const unsigned short* Ab = A + m0 * K;
    const unsigned short* Bb;
    if (MODE == 1)      Bb = BT + (m0 >> 12) * (size_t)589824 + (size_t)n0 * K;
    else if (MODE == 4) Bb = BT + (size_t)b * 589824 + (size_t)n0 * K;
    else                Bb = BT + (size_t)n0 * K;

    f32x4 zero = {0.f, 0.f, 0.f, 0.f};
    f32x4 acc[4][4];
#pragma unroll
    for (int i = 0; i < 4; ++i)
#pragma unroll
        for (int j = 0; j < 4; ++j) acc[i][j] = zero;

    auto STAGE = [&](int t) {
        char* base = SM + (t % 3) * 24576;
        {
            const int c = tid;                        // A: 128x32
            const int rp = c >> 3;
            const int ch = (c & 7) ^ (rp & 7);
            const int srow = rp * 2 + (ch >> 2);
            const int sk = (ch & 3) * 8;
            GLOAD16(Ab + (size_t)srow * K + t * 32 + sk, base + c * 16);
        }
#pragma unroll
        for (int ev = 0; ev < 2; ++ev) {
            const int c = ev * 512 + tid;             // B: 256x32
            const int rp = c >> 3;
            const int ch = (c & 7) ^ (rp & 7);
            const int srow = rp * 2 + (ch >> 2);
            const int sk = (ch & 3) * 8;
            GLOAD16(Bb + (size_t)srow * K + t * 32 + sk, base + 8192 + c * 16);
        }
    };

    STAGE(0);
    STAGE(1);

    for (int t = 0; t < NT; ++t) {
        if (t < NT - 1) asm volatile("s_waitcnt vmcnt(3)" ::: "memory");
        else            asm volatile("s_waitcnt vmcnt(0)" ::: "memory");
        __builtin_amdgcn_s_barrier();
        __builtin_amdgcn_sched_barrier(0);

        const char* la = SM + (t % 3) * 24576;
        const char* lb = la + 8192;

        bf16x8 af[4], bfr[4];
#pragma unroll
        for (int ni = 0; ni < 4; ++ni) {
            const int row = wn * 64 + ni * 16 + lr;
            const int rp = row >> 1;
            const int ch = (row & 1) * 4 + lq;
            bfr[ni] = *(const bf16x8*)(lb + rp * 128 + ((ch ^ (rp & 7)) << 4));
        }
#pragma unroll
        for (int mi = 0; mi < 4; ++mi) {
            const int row = wm * 64 + mi * 16 + lr;
            const int rp = row >> 1;
            const int ch = (row & 1) * 4 + lq;
            af[mi] = *(const bf16x8*)(la + rp * 128 + ((ch ^ (rp & 7)) << 4));
        }
        __builtin_amdgcn_s_setprio(1);
#pragma unroll
        for (int mi = 0; mi < 4; ++mi)
#pragma unroll
            for (int ni = 0; ni < 4; ++ni)
                acc[mi][ni] = MFMA16(af[mi], bfr[ni], acc[mi][ni]);
        __builtin_amdgcn_s_setprio(0);

        __builtin_amdgcn_sched_barrier(0);
        if (t + 2 < NT) STAGE(t + 2);
    }

    float bb[4];
#pragma unroll
    for (int ni = 0; ni < 4; ++ni) {
        const int col = n0 + wn * 64 + ni * 16 + lr;
        bb[ni] = (MODE == 1) ? (bias[(m0 >> 12) * 768 + col] + ldscal(bp, col, f32m)) : 0.f;
    }

    // drain K-loop LDS reads, then reuse LDS for epilogue repack
    asm volatile("s_waitcnt lgkmcnt(0)" ::: "memory");
    __builtin_amdgcn_s_barrier();

    if (MODE == 1 && f32m) {
        float* Lf = (float*)SM + wave * 2176;        // 32 rows x 68 f32
#pragma unroll
        for (int mh = 0; mh < 2; ++mh) {
#pragma unroll
            for (int mp = 0; mp < 2; ++mp)
#pragma unroll
                for (int ni = 0; ni < 4; ++ni)
#pragma unroll
                    for (int r = 0; r < 4; ++r) {
                        const int lrow = mp * 16 + lq * 4 + r;
                        const int lcol = ni * 16 + lr;
                        Lf[lrow * 68 + lcol] = acc[mh * 2 + mp][ni][r] + bb[ni];
                    }
#pragma unroll
            for (int rr = 0; rr < 8; ++rr) {
                const int lrow = rr * 4 + lq;
                const int lcol = lr * 4;
                f32x4 v = *(const f32x4*)&Lf[lrow * 68 + lcol];
                const size_t grow = m0 + (size_t)(wm * 64 + mh * 32 + lrow);
                __builtin_nontemporal_store(v, (f32x4*)&oF[grow * 768 + n0 + wn * 64 + lcol]);
            }
        }
    } else {
        // bf16 coalesced store: repack 64x64 wave tile via LDS, u16x8 stores
        unsigned short* Lh = (unsigned short*)SM + wave * 2304;   // 32 x 72 u16
#pragma unroll
        for (int mh = 0; mh < 2; ++mh) {
#pragma unroll
            for (int mp = 0; mp < 2; ++mp)
#pragma unroll
                for (int ni = 0; ni < 4; ++ni)
#pragma unroll
                    for (int r = 0; r < 4; ++r) {
                        const int lrow = mp * 16 + lq * 4 + r;
                        const int lcol = ni * 16 + lr;
                        Lh[lrow * 72 + lcol] = f2bf(acc[mh * 2 + mp][ni][r] + bb[ni]);
                    }
#pragma unroll
            for (int rr = 0; rr < 4; ++rr) {
                const int lrow = rr * 8 + (lane >> 3);
                const int lcol = (lane & 7) * 8;
                u16x8 v = *(const u16x8*)&Lh[lrow * 72 + lcol];
                const size_t grow = m0 + (size_t)(wm * 64 + mh * 32 + lrow);
                const int gcol = n0 + wn * 64 + lcol;
                if (MODE == 4)
                    *(u16x8*)&o0[(size_t)b * 1179648 + grow * 768 + gcol] = v;
                else if (MODE == 1)
                    __builtin_nontemporal_store(v, (u16x8*)&o0[grow * 768 + gcol]);
                else
                    *(u16x8*)&o0[grow * 768 + gcol] = v;
            }
        }
    }
}

// ---------------------------------------------------------------------------
// attn_mb: fused attn + mb_build + beff partials (validated r14-r17).
// ---------------------------------------------------------------------------
__global__ __launch_bounds__(512)
void attn_mb(const unsigned short* __restrict__ P,
             const unsigned short* __restrict__ WqkT,
             const float* __restrict__ s,
             const void* __restrict__ bqkv,
             const unsigned short* __restrict__ WprojT,
             const unsigned short* __restrict__ tf,
             unsigned short* __restrict__ MbT,
             float* __restrict__ beff)
{
    __shared__ float S[64][64];
    __shared__ float nq[64], nk[64], uq[64], uk[64];
    __shared__ float sb[768];
    __shared__ float bkv[64];
    __shared__ float bvv[64];
    __shared__ unsigned short Pl[64 * 72];
    const bool f32m = is_f32(tf);
    const int bh = blockIdx.x;
    const int b = bh / 12, h = bh % 12;
    const unsigned short* Pq = P + (size_t)b * 1179648 + (size_t)(h * 64) * 768;
    const unsigned short* Wq = WqkT + (size_t)(h * 64) * 768;
    const unsigned short* Pk = Pq + 589824;
    const unsigned short* Wk = Wq + 589824;
    const int tid = threadIdx.x;
    const int wave = tid >> 6;
    const int lane = tid & 63;
    const int lr = lane & 15;
    const int lq = lane >> 4;

    for (int i = tid; i < 768; i += 512) sb[i] = s[b * 768 + i];
    if (tid < 64)       bkv[tid] = ldscal(bqkv, 768 + h * 64 + tid, f32m);
    else if (tid < 128) bvv[tid - 64] = ldscal(bqkv, 1536 + h * 64 + (tid - 64), f32m);

    f32x4 zero = {0.f, 0.f, 0.f, 0.f};
    f32x4 acc[4][4];
#pragma unroll
    for (int i = 0; i < 4; ++i)
#pragma unroll
        for (int j = 0; j < 4; ++j) acc[i][j] = zero;

    for (int ks = 0; ks < 3; ++ks) {
        const int j0 = wave * 96 + ks * 32 + lq * 8;
        u16x8 qa[4], ka[4];
#pragma unroll
        for (int mi = 0; mi < 4; ++mi)
            qa[mi] = *(const u16x8*)&Pq[(size_t)(mi * 16 + lr) * 768 + j0];
#pragma unroll
        for (int ni = 0; ni < 4; ++ni)
            ka[ni] = *(const u16x8*)&Wk[(size_t)(ni * 16 + lr) * 768 + j0];
#pragma unroll
        for (int mi = 0; mi < 4; ++mi)
#pragma unroll
            for (int ni = 0; ni < 4; ++ni)
                acc[mi][ni] = MFMA16(__builtin_bit_cast(bf16x8, qa[mi]),
                                     __builtin_bit_cast(bf16x8, ka[ni]),
                                     acc[mi][ni]);
    }
    __syncthreads();

    for (int ww = 0; ww < 8; ++ww) {
        if (wave == ww) {
#pragma unroll
            for (int mi = 0; mi < 4; ++mi)
#pragma unroll
                for (int ni = 0; ni < 4; ++ni)
#pragma unroll
                    for (int r = 0; r < 4; ++r) {
                        const int d = mi * 16 + lq * 4 + r;
                        const int e = ni * 16 + lr;
                        if (ww == 0) S[d][e] = acc[mi][ni][r];
                        else         S[d][e] += acc[mi][ni][r];
                    }
        }
        __syncthreads();
    }

    const int d   = tid >> 3;
    const int oct = tid & 7;
    {
        const unsigned short* pqr = Pq + (size_t)d * 768 + oct * 96;
        const unsigned short* wqr = Wq + (size_t)d * 768 + oct * 96;
        const unsigned short* pkr = Pk + (size_t)d * 768 + oct * 96;
        const unsigned short* wkr = Wk + (size_t)d * 768 + oct * 96;
        float a_nq = 0.f, a_uq = 0.f, a_nk = 0.f, a_uk = 0.f;
        for (int i = 0; i < 12; ++i) {
            u16x8 vp = *(const u16x8*)&pqr[i * 8];
            u16x8 vw = *(const u16x8*)&wqr[i * 8];
            u16x8 kp = *(const u16x8*)&pkr[i * 8];
            u16x8 kw = *(const u16x8*)&wkr[i * 8];
#pragma unroll
            for (int j = 0; j < 8; ++j) {
                const float wqv = bf2f(vw[j]);
                const float wkv = bf2f(kw[j]);
                const float sj = sb[oct * 96 + i * 8 + j];
                a_nq += bf2f(vp[j]) * wqv;
                a_uq += sj * wqv;
                a_nk += bf2f(kp[j]) * wkv;
                a_uk += sj * wkv;
            }
        }
        a_nq += __shfl_xor(a_nq, 1); a_nq += __shfl_xor(a_nq, 2); a_nq += __shfl_xor(a_nq, 4);
        a_uq += __shfl_xor(a_uq, 1); a_uq += __shfl_xor(a_uq, 2); a_uq += __shfl_xor(a_uq, 4);
        a_nk += __shfl_xor(a_nk, 1); a_nk += __shfl_xor(a_nk, 2); a_nk += __shfl_xor(a_nk, 4);
        a_uk += __shfl_xor(a_uk, 1); a_uk += __shfl_xor(a_uk, 2); a_uk += __shfl_xor(a_uk, 4);
        if (oct == 0) { nq[d] = a_nq; uq[d] = a_uq; nk[d] = a_nk; uk[d] = a_uk; }
    }
    __syncthreads();

    {
        const float tv  = f32m ? ((const float*)tf)[h] : bf2f(tf[h]);
        const float bqd = ldscal(bqkv, h * 64 + d, f32m);
        const float uqd = uq[d];
        const float nqf = nq[d] + 2.f * bqd * uqd + 4096.f * bqd * bqd;
        const float qn  = fmaxf(sqrtf(fmaxf(nqf, 0.f)), 1e-12f);
        float vals[8];
        float mx = -1e30f;
#pragma unroll
        for (int i = 0; i < 8; ++i) {
            const int e = oct * 8 + i;
            const float bke = bkv[e];
            const float nkf = nk[e] + 2.f * bke * uk[e] + 4096.f * bke * bke;
            const float kn  = fmaxf(sqrtf(fmaxf(nkf, 0.f)), 1e-12f);
            const float sv  = S[d][e] + bqd * uk[e] + uqd * bke + 4096.f * bqd * bke;
            const float val = sv / (qn * kn) * tv;
            vals[i] = val;
            mx = fmaxf(mx, val);
        }
        mx = fmaxf(mx, __shfl_xor(mx, 1));
        mx = fmaxf(mx, __shfl_xor(mx, 2));
        mx = fmaxf(mx, __shfl_xor(mx, 4));
        float sum = 0.f;
#pragma unroll
        for (int i = 0; i < 8; ++i) { vals[i] = __expf(vals[i] - mx); sum += vals[i]; }
        sum += __shfl_xor(sum, 1);
        sum += __shfl_xor(sum, 2);
        sum += __shfl_xor(sum, 4);
        const float inv = 1.0f / sum;
#pragma unroll
        for (int i = 0; i < 8; ++i) {
            const int e = oct * 8 + i;
            Pl[e * 72 + d] = f2bf(vals[i] * inv);
        }
    }
    __syncthreads();

    f32x4 accm[4][6];
#pragma unroll
    for (int i = 0; i < 4; ++i)
#pragma unroll
        for (int j = 0; j < 6; ++j) accm[i][j] = zero;

#pragma unroll
    for (int ks = 0; ks < 2; ++ks) {
        bf16x8 af[4], bfr[6];
#pragma unroll
        for (int mi = 0; mi < 4; ++mi)
            af[mi] = *(const bf16x8*)&Pl[(mi * 16 + lr) * 72 + ks * 32 + lq * 8];
#pragma unroll
        for (int ni = 0; ni < 6; ++ni) {
            const int j = wave * 96 + ni * 16 + lr;
            bfr[ni] = *(const bf16x8*)&WprojT[(size_t)j * 768 + h * 64 + ks * 32 + lq * 8];
        }
#pragma unroll
        for (int mi = 0; mi < 4; ++mi)
#pragma unroll
            for (int ni = 0; ni < 6; ++ni)
                accm[mi][ni] = MFMA16(af[mi], bfr[ni], accm[mi][ni]);
    }

#pragma unroll
    for (int ni = 0; ni < 6; ++ni) {
        const int j = wave * 96 + ni * 16 + lr;
        float part = 0.f;
#pragma unroll
        for (int mi = 0; mi < 4; ++mi) {
            const int e = mi * 16 + lq * 4;
            u16x4 pk;
#pragma unroll
            for (int r = 0; r < 4; ++r) {
                pk[r] = f2bf(accm[mi][ni][r]);
                part += accm[mi][ni][r] * bvv[e + r];
            }
            *(u16x4*)&MbT[(size_t)b * 589824 + (size_t)j * 768 + h * 64 + e] = pk;
        }
        atomicAdd(&beff[b * 768 + j], part);
    }
}

// ---------------------------------------------------------------------------
extern "C" void kernel_launch(void* const* d_in, const int* in_sizes, int n_in,
                              void* d_out, int out_size, void* d_ws, size_t ws_size,
                              hipStream_t stream)
{
    const void* x    = d_in[0];
    const void* Wqkv = d_in[1];
    const void* bqkv = d_in[2];
    const void* Wp   = d_in[3];
    const void* bp   = d_in[4];
    const unsigned short* tf = (const unsigned short*)d_in[5];

    char* w = (char*)d_ws;
    unsigned short* xbT    = (unsigned short*)(w);                  // [768][65536]
    unsigned short* xb     = (unsigned short*)(w + 100663296);      // [65536][768]
    unsigned short* G      = (unsigned short*)(w + 201326592);      // [16][768][768]
    unsigned short* P      = (unsigned short*)(w + 220200960);      // [16][1536][768]
    unsigned short* PT     = (unsigned short*)(w + 257949696);      // [16][768][768]
    unsigned short* MbT    = (unsigned short*)(w + 276824064);      // [16][768][768]
    unsigned short* WqkT   = (unsigned short*)(w + 295698432);      // [1536][768]
    unsigned short* Wv_bf  = (unsigned short*)(w + 298057728);      // [768][768]
    unsigned short* WprojT = (unsigned short*)(w + 299237376);      // [768][768]
    float*          sB     = (float*)(w + 301989888);               // [16][768]
    float*          beff   = (float*)(w + 302039040);               // [16][768]
    // total ws use: 302088192 B

    hipMemsetAsync(sB, 0, 98304, stream);   // sB + beff (adjacent)
    prep_all<<<dim3(13008), dim3(256), 0, stream>>>(x, xb, xbT, sB, Wqkv, Wp,
                                                    WqkT, Wv_bf, WprojT, tf);

    gemmG<<<dim3(336), dim3(256), 0, stream>>>(xbT, G);
    gemmH<4><<<dim3(576), dim3(512), 0, stream>>>(WqkT, G, nullptr, nullptr, P, nullptr, tf);
    attn_mb<<<dim3(192), dim3(512), 0, stream>>>(P, WqkT, sB, bqkv, WprojT, tf, MbT, beff);
    gemmH<2><<<dim3(288), dim3(512), 0, stream>>>(MbT, Wv_bf, nullptr, nullptr, PT, nullptr, tf);
    gemmH<1><<<dim3(1536), dim3(512), 0, stream>>>(xb, PT, beff, bp,
        (unsigned short*)d_out, (float*)d_out, tf);
}